// Round 16
// baseline (110.863 us; speedup 1.0000x reference)
//
#include <hip/hip_runtime.h>

// x: (128, 55, 55, 96) NHWC fp32; kernel: (96, 5, 5) fp32 depthwise; out = x + dwconv(x,k)
#define NB 128
#define HW 55
#define IMG (HW * HW)            // 3025
#define CH 96
#define GROUPS 24                // float4 channel-groups
#define TAPS 25
#define NPIX (NB * IMG)          // 387,200
#define RSTRIP 5                 // rows per conv block (55 = 5*11)
#define NSTRIP (HW / RSTRIP)     // 11
#define NWG1 (NB * NSTRIP)       // 1408 conv blocks
#define TOTALF4 (NPIX * GROUPS)  // 9,292,800
#define NWG2 (TOTALF4 / 256)     // 36,300 stream blocks (exact)
#define SROWS (RSTRIP + 4)       // 9 staged rows (halo +-2)
#define GCHUNK 4                 // compact-buffer group capacity
#define SLOTG 32                 // per-group slot capacity
#define NXCD 8
#define SPIX (RSTRIP * HW)       // 275 strip pixels
#define STAGEN (SROWS * HW)      // 495 staged pixels
#define BITEMS (RSTRIP * HW * GROUPS)
#define PCH_FB 128               // (unused by split path)

typedef float v4f __attribute__((ext_vector_type(4)));

// ---- workspace ----
// float4 wslot[24][SLOTG]; int2 dslot[24][SLOTG] ({dh+2, dw}); int tapflag[24];
// int gact[24]; int nga, nspad, amask; pad; v4f cvbuf[NPIX][<=GCHUNK]

__global__ void repack_kernel(const float* __restrict__ k,
                              float4* __restrict__ wslot,
                              int2* __restrict__ dslot,
                              int* __restrict__ tapflag,
                              int* __restrict__ gact,
                              int* __restrict__ nga,
                              int* __restrict__ nspad,
                              int* __restrict__ amask) {
    __shared__ int s_ns[GROUPS];
    int g = threadIdx.x;
    if (g < GROUPS) {
        int ns = 0;
        for (int tap = 0; tap < TAPS; ++tap) {
            float w0 = k[(4 * g + 0) * TAPS + tap];
            float w1 = k[(4 * g + 1) * TAPS + tap];
            float w2 = k[(4 * g + 2) * TAPS + tap];
            float w3 = k[(4 * g + 3) * TAPS + tap];
            if (w0 != 0.f || w1 != 0.f || w2 != 0.f || w3 != 0.f) {
                int dh = tap / 5 - 2, dw = tap % 5 - 2;
                wslot[g * SLOTG + ns] = make_float4(w0, w1, w2, w3);
                dslot[g * SLOTG + ns] = make_int2(dh + 2, dw);
                ++ns;
            }
        }
        for (int s = ns; s < SLOTG; ++s) {           // pads: weight 0 -> contribute 0
            wslot[g * SLOTG + s] = make_float4(0.f, 0.f, 0.f, 0.f);
            dslot[g * SLOTG + s] = make_int2(2, 0);  // center, always valid
        }
        tapflag[g] = (ns > 0) ? 1 : 0;
        s_ns[g] = ns;
    }
    __syncthreads();
    if (threadIdx.x == 0) {
        int na = 0, m = 0, msk = 0;
        for (int gg = 0; gg < GROUPS; ++gg)
            if (s_ns[gg] > 0) {
                gact[na++] = gg;
                msk |= (1 << gg);
                m = m > s_ns[gg] ? m : s_ns[gg];
            }
        *nga = na;
        *nspad = (m + 7) & ~7;
        *amask = msk;
    }
}

// ---- K1: conv deltas for first min(nga,GCHUNK) active groups -> compact cvbuf ----
__global__ __launch_bounds__(256) void conv_kernel(const float* __restrict__ x,
                                                   const float4* __restrict__ wslot,
                                                   const int2* __restrict__ dslot,
                                                   const int* __restrict__ gact,
                                                   const int* __restrict__ p_nga,
                                                   const int* __restrict__ p_nspad,
                                                   v4f* __restrict__ cvbuf) {
    __shared__ v4f s_x[GCHUNK * STAGEN];      // planar halo tile 31680 B
    __shared__ float4 s_w[GCHUNK * 8];
    __shared__ int s_d[GCHUNK * 8];           // packed (dh+2)<<8|(dw+2)

    int cn = *p_nga;
    if (cn > GCHUNK) cn = GCHUNK;
    if (cn == 0) return;
    const int nsb = (*p_nspad) >> 3;

    const int q = NWG1 / NXCD, r = NWG1 % NXCD;
    int xcd = blockIdx.x & (NXCD - 1);
    int bidx = blockIdx.x >> 3;
    int swz = (xcd < r ? xcd * (q + 1) : r * (q + 1) + (xcd - r) * q) + bidx;

    const int n = swz / NSTRIP;
    const int strip = swz % NSTRIP;
    const int h0 = strip * RSTRIP;
    const int tid = threadIdx.x;
    const int pixbase = n * IMG + h0 * HW;
    const v4f* x4 = (const v4f*)x;

    if (tid < cn * 8) {                       // stage first slot batch
        int ci = tid >> 3, s = tid & 7;
        int gg = gact[ci];
        s_w[tid] = wslot[gg * SLOTG + s];
        int2 dd = dslot[gg * SLOTG + s];
        s_d[tid] = (dd.x << 8) | (dd.y + 2);
    }
    // stage x halo tile (coalesced; out-of-image rows -> zeros); planar layout
    const int stcnt = STAGEN * cn;
    const int wcn = HW * cn;
    for (int i = tid; i < stcnt; i += 256) {
        int srow = i / wcn;
        int rem2 = i - srow * wcn;
        int pix = rem2 / cn;
        int ci = rem2 - pix * cn;
        int h = h0 - 2 + srow;
        v4f v = {0.f, 0.f, 0.f, 0.f};
        if ((unsigned)h < (unsigned)HW)
            v = x4[(n * IMG + h * HW + pix) * GROUPS + gact[ci]];
        s_x[ci * STAGEN + srow * HW + pix] = v;
    }
    __syncthreads();

    // lane-dense conv; lane order ci-fastest -> fully dense 16B/lane stores
    const int acnt = SPIX * cn;
    for (int j = tid; j < acnt; j += 256) {
        int pa = j / cn;
        int ci = j - pa * cn;
        int rr = pa / HW;
        int pix = pa - rr * HW;
        const v4f* sxg = s_x + ci * STAGEN;
        v4f acc = {0.f, 0.f, 0.f, 0.f};
#pragma unroll
        for (int si = 0; si < 8; ++si) {
            int d = s_d[ci * 8 + si];
            int srow = rr + (d >> 8);
            int pix2 = pix + (d & 255) - 2;
            bool valid = (unsigned)pix2 < (unsigned)HW;
            float sc = valid ? 1.f : 0.f;
            int p2 = valid ? pix2 : 0;
            v4f xv = sxg[srow * HW + p2];
            float4 wv = s_w[ci * 8 + si];
            acc.x += (wv.x * sc) * xv.x;
            acc.y += (wv.y * sc) * xv.y;
            acc.z += (wv.z * sc) * xv.z;
            acc.w += (wv.w * sc) * xv.w;
        }
        for (int sb = 1; sb < nsb; ++sb) {    // rare tail (generality; none here)
            int gg = gact[ci];
#pragma unroll
            for (int si = 0; si < 8; ++si) {
                int s = sb * 8 + si;
                int2 dd = dslot[gg * SLOTG + s];
                int srow = rr + dd.x;
                int pix2 = pix + dd.y;
                bool valid = (unsigned)pix2 < (unsigned)HW;
                float sc = valid ? 1.f : 0.f;
                int p2 = valid ? pix2 : 0;
                v4f xv = sxg[srow * HW + p2];
                float4 wv = wslot[gg * SLOTG + s];
                acc.x += (wv.x * sc) * xv.x;
                acc.y += (wv.y * sc) * xv.y;
                acc.z += (wv.z * sc) * xv.z;
                acc.w += (wv.w * sc) * xv.w;
            }
        }
        __builtin_nontemporal_store(acc, &cvbuf[(size_t)(pixbase + pa) * cn + ci]);
    }
}

// ---- K2: barrier-free dense stream: out = x (+ cv gather for active lanes) ----
__global__ __launch_bounds__(256) void stream_kernel(const float* __restrict__ x,
                                                     const v4f* __restrict__ cvbuf,
                                                     const float4* __restrict__ wslot,
                                                     const int2* __restrict__ dslot,
                                                     const int* __restrict__ p_amask,
                                                     const int* __restrict__ p_nspad,
                                                     float* __restrict__ out) {
    const int q = NWG2 / NXCD, r = NWG2 % NXCD;
    int xcd = blockIdx.x & (NXCD - 1);
    int bidx = blockIdx.x >> 3;
    int swz = (xcd < r ? xcd * (q + 1) : r * (q + 1) + (xcd - r) * q) + bidx;

    const int i = swz * 256 + threadIdx.x;
    const int g = i % GROUPS;
    const int pixel = i / GROUPS;
    const v4f* x4 = (const v4f*)x;
    v4f acc = x4[i];                          // dense coalesced residual

    const int amask = *p_amask;               // uniform scalar load
    const int ngtot = __popc(amask);
    const bool act = (amask >> g) & 1;
    if (act) {
        int aidx = __popc(amask & ((1u << g) - 1));
        int cn = ngtot < GCHUNK ? ngtot : GCHUNK;
        if (aidx < GCHUNK)
            acc += cvbuf[(size_t)pixel * cn + aidx];
    }
    if (ngtot > GCHUNK) {                     // uniform branch; never taken here
        int aidx = act ? __popc(amask & ((1u << g) - 1)) : 0;
        if (act && aidx >= GCHUNK) {          // scattered conv (correct, slow)
            int rem = pixel % IMG;
            int h = rem / HW, w = rem - h * HW;
            const float* xb = x + (size_t)i * 4;
            int nsb = (*p_nspad) >> 3;
            for (int sb = 0; sb < nsb; ++sb) {
#pragma unroll
                for (int si = 0; si < 8; ++si) {
                    int s = sb * 8 + si;
                    int2 dd = dslot[g * SLOTG + s];
                    int dh2 = dd.x, dw = dd.y;
                    bool valid = ((unsigned)(h + dh2 - 2) < (unsigned)HW) &
                                 ((unsigned)(w + dw) < (unsigned)HW);
                    float sc = valid ? 1.f : 0.f;
                    int off = valid ? ((dh2 - 2) * HW * CH + dw * CH) : 0;
                    v4f xv = *(const v4f*)(xb + off);
                    float4 wv = wslot[g * SLOTG + s];
                    acc.x += (wv.x * sc) * xv.x;
                    acc.y += (wv.y * sc) * xv.y;
                    acc.z += (wv.z * sc) * xv.z;
                    acc.w += (wv.w * sc) * xv.w;
                }
            }
        }
    }
    __builtin_nontemporal_store(acc, &((v4f*)out)[i]);  // dense 16B/lane
}

// ---- Fallback (ws too small): monolithic, reads raw k — correctness only ----
__global__ __launch_bounds__(256) void fallback_kernel(const float* __restrict__ x,
                                                       const float* __restrict__ kraw,
                                                       float* __restrict__ out) {
    int t = blockIdx.x * 256 + threadIdx.x;
    if (t >= TOTALF4) return;
    int g = t % GROUPS;
    int pixel = t / GROUPS;
    int rem = pixel % IMG;
    int h = rem / HW;
    int w = rem - h * HW;
    int base = pixel * CH + g * 4;
    const float4 xc = *reinterpret_cast<const float4*>(x + base);
    float4 acc = make_float4(xc.x, xc.y, xc.z, xc.w);
#pragma unroll
    for (int dh = -2; dh <= 2; ++dh)
#pragma unroll
        for (int dw = -2; dw <= 2; ++dw) {
            const int tap = (dh + 2) * 5 + (dw + 2);
            const bool valid = ((unsigned)(h + dh) < (unsigned)HW) &
                               ((unsigned)(w + dw) < (unsigned)HW);
            const float vs = valid ? 1.0f : 0.0f;
            const int off = valid ? (dh * HW * CH + dw * CH) : 0;
            const float4 xv = *reinterpret_cast<const float4*>(x + base + off);
            acc.x += (kraw[(g * 4 + 0) * TAPS + tap] * vs) * xv.x;
            acc.y += (kraw[(g * 4 + 1) * TAPS + tap] * vs) * xv.y;
            acc.z += (kraw[(g * 4 + 2) * TAPS + tap] * vs) * xv.z;
            acc.w += (kraw[(g * 4 + 3) * TAPS + tap] * vs) * xv.w;
        }
    *reinterpret_cast<float4*>(out + base) = acc;
}

extern "C" void kernel_launch(void* const* d_in, const int* in_sizes, int n_in,
                              void* d_out, int out_size, void* d_ws, size_t ws_size,
                              hipStream_t stream) {
    const float* x = (const float*)d_in[0];
    const float* k = (const float*)d_in[1];
    float* out = (float*)d_out;

    const size_t sz_wslot = (size_t)GROUPS * SLOTG * sizeof(float4);   // 12288
    const size_t sz_dslot = (size_t)GROUPS * SLOTG * sizeof(int2);     // 6144
    const size_t sz_flag = GROUPS * sizeof(int);
    const size_t sz_gact = GROUPS * sizeof(int);
    const size_t sz_scalars = 3 * sizeof(int);
    size_t tab_bytes = sz_wslot + sz_dslot + sz_flag + sz_gact + sz_scalars;
    tab_bytes = (tab_bytes + 15) & ~(size_t)15;                        // align cvbuf
    const size_t sz_cvbuf = (size_t)NPIX * GCHUNK * sizeof(v4f);       // 24.8 MB

    if (ws_size >= tab_bytes + sz_cvbuf) {
        char* p = (char*)d_ws;
        float4* wslot = (float4*)p;  p += sz_wslot;
        int2* dslot = (int2*)p;      p += sz_dslot;
        int* tapflag = (int*)p;      p += sz_flag;
        int* gact = (int*)p;         p += sz_gact;
        int* nga = (int*)p;          p += sizeof(int);
        int* nspad = (int*)p;        p += sizeof(int);
        int* amask = (int*)p;
        v4f* cvbuf = (v4f*)((char*)d_ws + tab_bytes);

        repack_kernel<<<1, 64, 0, stream>>>(k, wslot, dslot, tapflag, gact,
                                            nga, nspad, amask);
        conv_kernel<<<NWG1, 256, 0, stream>>>(x, wslot, dslot, gact, nga, nspad,
                                              cvbuf);
        stream_kernel<<<NWG2, 256, 0, stream>>>(x, cvbuf, wslot, dslot, amask,
                                                nspad, out);
    } else {
        fallback_kernel<<<NWG2, 256, 0, stream>>>(x, k, out);
    }
}